// Round 8
// baseline (372.448 us; speedup 1.0000x reference)
//
#include <hip/hip_runtime.h>

#define T_LEN 1024
#define B_TOTAL 8192
#define NITER 256  // T_LEN / 4

typedef _Float16 f16x8 __attribute__((ext_vector_type(8)));
typedef float f32x4 __attribute__((ext_vector_type(4)));

__device__ __forceinline__ float fast_tanh(float x) {
    // tanh(x) = 1 - 2/(exp(2x)+1); v_exp_f32 + v_rcp_f32, err ~1e-6.
    float e = __builtin_amdgcn_exp2f(x * 2.8853900817779268f); // 2*log2(e)
    float r = __builtin_amdgcn_rcpf(e + 1.0f);
    return fmaf(-2.0f, r, 1.0f);
}

#define MFMA(a, b, c) __builtin_amdgcn_mfma_f32_16x16x32_f16((a), (b), (c), 0, 0, 0)

// Deep-pipelined 2-wave layer split per 16 batches.
//   wave0 (producer): layer-1 recurrence; writes h1(t) into a 16-slot LDS ring.
//   wave1 (consumer): layer-2 recurrence + y head, lagging 8 steps (2 iters).
// One s_barrier per 4-step iteration. Consumer reads slots written >=2
// barriers earlier and prefetches 1 step ahead -> LDS latency fully off the
// chain (the round-7 failure: zero-depth handoff put ~240 cyc of LDS latency
// on the chain). Ring half h is rewritten every 4 iters, read 2 iters after
// write -> ordering guaranteed by barriers alone.
// Unit-relabeling (round-6-verified): A-row m <- weight row 8*(m>>2)+(m&3)
// (lo) / +4 (hi); lane (bl,g)'s D regs are storage slots {8g+r, 8g+4+r} =
// exactly its next B-fragment k-slots -> no transpose anywhere.
__global__ __launch_bounds__(128, 1) void rnn_pipe_kernel(
    const float* __restrict__ x,     const float* __restrict__ h0,
    const float* __restrict__ W_ih0, const float* __restrict__ W_hh0,
    const float* __restrict__ b_ih0, const float* __restrict__ b_hh0,
    const float* __restrict__ W_ih1, const float* __restrict__ W_hh1,
    const float* __restrict__ b_ih1, const float* __restrict__ b_hh1,
    const float* __restrict__ W_out, const float* __restrict__ b_out,
    float* __restrict__ out)
{
    // 16 slots x 16 rows x 40 halves (80B row stride -> 2-way alias = free).
    __shared__ __align__(16) _Float16 ring[16][16][40];

    const int tid  = threadIdx.x;
    const int wid  = tid >> 6;            // 0 = producer, 1 = consumer
    const int lane = tid & 63;
    const int bl   = lane & 15;           // batch column (n-index / A-row)
    const int hi   = lane >> 4;           // lane quad g
    const int s0   = hi * 8;              // storage-slot base
    const int gb   = blockIdx.x * 16 + bl;

    const int ulo = 8 * (bl >> 2) + (bl & 3); // weight row for A-lo row bl
    const int uhi = ulo + 4;

    if (wid == 0) {
        // ================= producer: layer 1 =================
        f16x8 whh0_lo, whh0_hi;
#pragma unroll
        for (int e = 0; e < 8; ++e) {
            whh0_lo[e] = (_Float16)W_hh0[ulo * 32 + s0 + e];
            whh0_hi[e] = (_Float16)W_hh0[uhi * 32 + s0 + e];
        }
        f32x4 c0lo, c0hi, wi0lo, wi0hi;
#pragma unroll
        for (int r = 0; r < 4; ++r) {
            const int u = s0 + r, uh = s0 + 4 + r;
            c0lo[r] = b_ih0[u]  + b_hh0[u];
            c0hi[r] = b_ih0[uh] + b_hh0[uh];
            wi0lo[r] = W_ih0[u];
            wi0hi[r] = W_ih0[uh];
        }
        f16x8 Y1;
#pragma unroll
        for (int e = 0; e < 8; ++e)
            Y1[e] = (_Float16)h0[(size_t)gb * 32 + s0 + e];

        const float* xp = x + (size_t)gb * T_LEN;
        float h1f[8];
        float4 xq = *(const float4*)(xp);

        for (int m = 0; m < NITER + 2; ++m) {
            if (m < NITER) {
                const int t = m * 4;
                const float4 xqn = (t + 4 < T_LEN) ? *(const float4*)(xp + t + 4) : xq;
#pragma unroll
                for (int u = 0; u < 4; ++u) {
                    const float xt = (u == 0) ? xq.x : (u == 1) ? xq.y : (u == 2) ? xq.z : xq.w;
                    f32x4 pre_lo, pre_hi;
#pragma unroll
                    for (int r = 0; r < 4; ++r) {
                        pre_lo[r] = fmaf(xt, wi0lo[r], c0lo[r]);
                        pre_hi[r] = fmaf(xt, wi0hi[r], c0hi[r]);
                    }
                    const f32x4 d1lo = MFMA(whh0_lo, Y1, pre_lo);
                    const f32x4 d1hi = MFMA(whh0_hi, Y1, pre_hi);
                    f16x8 Y1n;
#pragma unroll
                    for (int r = 0; r < 4; ++r) {
                        h1f[r]     = fast_tanh(d1lo[r]);
                        h1f[4 + r] = fast_tanh(d1hi[r]);
                        Y1n[r]     = (_Float16)h1f[r];
                        Y1n[4 + r] = (_Float16)h1f[4 + r];
                    }
                    *(f16x8*)&ring[((m & 3) << 2) + u][bl][s0] = Y1n;
                    Y1 = Y1n;
                }
                xq = xqn;
            }
            asm volatile("s_waitcnt lgkmcnt(0)" ::: "memory");
            __builtin_amdgcn_s_barrier();
            asm volatile("" ::: "memory");
        }
        // final h1 -> h_state[0]
        float* hs = out + (size_t)B_TOTAL * T_LEN;
#pragma unroll
        for (int r = 0; r < 4; ++r) {
            hs[(size_t)gb * 32 + s0 + r]     = h1f[r];
            hs[(size_t)gb * 32 + s0 + 4 + r] = h1f[4 + r];
        }
    } else {
        // ================= consumer: layer 2 + head (lag 8 steps) ==========
        f16x8 wih1_lo, wih1_hi, whh1_lo, whh1_hi, wout_f;
#pragma unroll
        for (int e = 0; e < 8; ++e) {
            wih1_lo[e] = (_Float16)W_ih1[ulo * 32 + s0 + e];
            wih1_hi[e] = (_Float16)W_ih1[uhi * 32 + s0 + e];
            whh1_lo[e] = (_Float16)W_hh1[ulo * 32 + s0 + e];
            whh1_hi[e] = (_Float16)W_hh1[uhi * 32 + s0 + e];
            wout_f[e]  = (bl == 0) ? (_Float16)W_out[s0 + e] : (_Float16)0.0f;
        }
        f32x4 c1lo, c1hi;
#pragma unroll
        for (int r = 0; r < 4; ++r) {
            const int u = s0 + r, uh = s0 + 4 + r;
            c1lo[r] = b_ih1[u]  + b_hh1[u];
            c1hi[r] = b_ih1[uh] + b_hh1[uh];
        }
        const float bo = b_out[0];
        const f32x4 zero4 = {0.f, 0.f, 0.f, 0.f};

        f16x8 Y2;
#pragma unroll
        for (int e = 0; e < 8; ++e)
            Y2[e] = (_Float16)h0[(size_t)(B_TOTAL + gb) * 32 + s0 + e];

        float* yp = out + (size_t)gb * T_LEN;
        float h2f[8];
        f16x8 Y1pre; // preloaded h1 for the current step

        for (int m = 0; m < NITER + 2; ++m) {
            if (m >= 2) {
                const int j = m - 2;     // producer iteration being consumed
                const int t = j * 4;
                if (j == 0)
                    Y1pre = *(const f16x8*)&ring[0][bl][s0];
                float yq0, yq1, yq2, yq3;
#pragma unroll
                for (int u = 0; u < 4; ++u) {
                    // recurrent half on own (old) h2 first
                    f32x4 d2lo = MFMA(whh1_lo, Y2, c1lo);
                    f32x4 d2hi = MFMA(whh1_hi, Y2, c1hi);

                    // prefetch next step's h1 (written >=1 iteration ago)
                    const int ns = (u < 3) ? ((j & 3) << 2) + u + 1
                                           : (((j + 1) & 3) << 2);
                    const f16x8 Y1nx = *(const f16x8*)&ring[ns][bl][s0];

                    d2lo = MFMA(wih1_lo, Y1pre, d2lo);
                    d2hi = MFMA(wih1_hi, Y1pre, d2hi);
                    f16x8 Y2n;
#pragma unroll
                    for (int r = 0; r < 4; ++r) {
                        h2f[r]     = fast_tanh(d2lo[r]);
                        h2f[4 + r] = fast_tanh(d2hi[r]);
                        Y2n[r]     = (_Float16)h2f[r];
                        Y2n[4 + r] = (_Float16)h2f[4 + r];
                    }

                    // y head: W_out in A-row 0 -> y[bl] = D[m=0][bl]
                    const f32x4 d3 = MFMA(wout_f, Y2n, zero4);
                    const float yv = d3[0] + bo;
                    if (u == 0) yq0 = yv; else if (u == 1) yq1 = yv; else if (u == 2) yq2 = yv; else yq3 = yv;

                    Y2 = Y2n;
                    Y1pre = Y1nx;
                }
                if (hi == 0) {
                    float4 yo; yo.x = yq0; yo.y = yq1; yo.z = yq2; yo.w = yq3;
                    *(float4*)(yp + t) = yo;
                }
            }
            __builtin_amdgcn_s_barrier();
            asm volatile("" ::: "memory");
        }
        // final h2 -> h_state[1]
        float* hs = out + (size_t)B_TOTAL * T_LEN;
#pragma unroll
        for (int r = 0; r < 4; ++r) {
            hs[(size_t)(B_TOTAL + gb) * 32 + s0 + r]     = h2f[r];
            hs[(size_t)(B_TOTAL + gb) * 32 + s0 + 4 + r] = h2f[4 + r];
        }
    }
}

extern "C" void kernel_launch(void* const* d_in, const int* in_sizes, int n_in,
                              void* d_out, int out_size, void* d_ws, size_t ws_size,
                              hipStream_t stream) {
    const float* x     = (const float*)d_in[0];
    const float* h0    = (const float*)d_in[1];
    const float* W_ih0 = (const float*)d_in[2];
    const float* W_hh0 = (const float*)d_in[3];
    const float* b_ih0 = (const float*)d_in[4];
    const float* b_hh0 = (const float*)d_in[5];
    const float* W_ih1 = (const float*)d_in[6];
    const float* W_hh1 = (const float*)d_in[7];
    const float* b_ih1 = (const float*)d_in[8];
    const float* b_hh1 = (const float*)d_in[9];
    const float* W_out = (const float*)d_in[10];
    const float* b_out = (const float*)d_in[11];
    float* out = (float*)d_out;

    dim3 grid(B_TOTAL / 16); // 512 blocks x 2 waves
    dim3 block(128);
    rnn_pipe_kernel<<<grid, block, 0, stream>>>(x, h0, W_ih0, W_hh0, b_ih0, b_hh0,
                                                W_ih1, W_hh1, b_ih1, b_hh1,
                                                W_out, b_out, out);
}